// Round 9
// baseline (388.764 us; speedup 1.0000x reference)
//
#include <hip/hip_runtime.h>

// VoxelEncoding — single-level bucket grouping + XCD-affine gather-interp.
//
// Measured r0-r8:
//   - 2M returning GLOBAL atomics: ~13-17 Gop/s wall (line-RMW at fabric),
//     scope/ILP-independent -> bucket to ~60K atomics (done, r7).
//   - k_main @ full voxel sort: 127-130 us, FETCH 278 MB = ~4.07M unique
//     (voxel,corner) emb lines + streams; stable across 6 rounds = the
//     random-line service roofline (~3.2 TB/s effective).
//   - Harness re-poison fill: 512 MB, ~80 us, inside the timed window every
//     iteration; also the top-5 visibility floor.
//   - r8 sort side ~174 us vs ~35 us BW-ideal; k_binsort exists only to
//     restore intra-bucket adjacency (a cache trick, not correctness).
//
// This round: DELETE the second sort level. A bucket (2048 voxels) bounds
// the emb working set to ~1 MB < 4 MB XCD-L2, so same-voxel dedup survives
// IF all blocks of a bucket run on one XCD. Steer with the round-robin
// dispatch heuristic (blockIdx % 8 -> XCD; wrong mapping costs speed only):
// bucket b=8c+x owns blocks blockIdx=(c*256+j)*8+x. CAP=16384 (pow2);
// pad blocks early-exit on an L2-hot gbase read. Out is written once per
// point at out[orig] -> order-independent -> correct for ANY grouping.
//
// Fast path (ws >= ~81 MB):
//   K_init   : gbase[b] = b*CAP
//   K_bucket : 8192 pts/wg (1024 thr): LDS hist of NB buckets (v>>11) ->
//              1 returning atomic per (wg,bucket) -> LDS-cursor append of
//              {x,y,z,orig}(16B)+v(4B) into CAP-strided regions
//   K_main_b : XCD-affine interp directly over bucket regions
// Fallback (ws >= 52 MB): r4 pipeline. Last resort: k_direct.

typedef float v4f __attribute__((ext_vector_type(4)));

// ==================== FAST PATH ====================

__global__ void k_init_gbase(unsigned* __restrict__ gbase, int NB, unsigned CAP) {
    int i = blockIdx.x * blockDim.x + threadIdx.x;
    if (i < NB) gbase[i] = (unsigned)i * CAP;
}

// ---- K_bucket: 8192 pts/wg (1024 thr, 8/thread), LDS bucket hist, coarse scatter ----
__global__ __launch_bounds__(1024) void k_bucket(
    const int*   __restrict__ p2v,
    const float* __restrict__ pts,
    unsigned*    __restrict__ gbase,
    unsigned*    __restrict__ vA,
    v4f*         __restrict__ recA,
    int N, int NB)
{
    __shared__ unsigned cnt[512];
    __shared__ unsigned cur[512];
    const int tid = threadIdx.x;
    const int i0 = (blockIdx.x * 1024 + tid) * 8;

    for (int b = tid; b < NB; b += 1024) cnt[b] = 0u;
    __syncthreads();

    int vv[8];
    const bool full = (i0 + 7 < N);
    if (full) {
        const int4 a = *(const int4*)(p2v + i0);
        const int4 b4 = *(const int4*)(p2v + i0 + 4);
        vv[0]=a.x; vv[1]=a.y; vv[2]=a.z; vv[3]=a.w;
        vv[4]=b4.x; vv[5]=b4.y; vv[6]=b4.z; vv[7]=b4.w;
        #pragma unroll
        for (int k = 0; k < 8; ++k) atomicAdd(&cnt[vv[k] >> 11], 1u);
    } else {
        for (int k = 0; k < 8; ++k)
            if (i0 + k < N) { vv[k] = p2v[i0 + k]; atomicAdd(&cnt[vv[k] >> 11], 1u); }
    }
    __syncthreads();

    // one global returning atomic per (wg, nonempty bucket)
    for (int b = tid; b < NB; b += 1024) {
        const unsigned c = cnt[b];
        cur[b] = c ? atomicAdd(&gbase[b], c) : 0u;
    }
    __syncthreads();

    if (full) {
        const v4f* p4 = (const v4f*)pts;
        const size_t fb = (size_t)3 * (size_t)(i0 >> 2);
        const v4f f0 = p4[fb], f1 = p4[fb+1], f2 = p4[fb+2];
        const v4f f3 = p4[fb+3], f4 = p4[fb+4], f5 = p4[fb+5];
        const float xs[8] = {f0.x, f0.w, f1.z, f2.y, f3.x, f3.w, f4.z, f5.y};
        const float ys[8] = {f0.y, f1.x, f1.w, f2.z, f3.y, f4.x, f4.w, f5.z};
        const float zs[8] = {f0.z, f1.y, f2.x, f2.w, f3.z, f4.y, f5.x, f5.w};
        #pragma unroll
        for (int k = 0; k < 8; ++k) {
            const unsigned pos = atomicAdd(&cur[vv[k] >> 11], 1u);
            v4f r; r.x = xs[k]; r.y = ys[k]; r.z = zs[k]; r.w = __int_as_float(i0 + k);
            recA[pos] = r;
            vA[pos] = (unsigned)vv[k];
        }
    } else {
        for (int k = 0; k < 8; ++k) {
            const int i = i0 + k;
            if (i >= N) break;
            const unsigned pos = atomicAdd(&cur[vv[k] >> 11], 1u);
            v4f r;
            r.x = pts[3*(size_t)i]; r.y = pts[3*(size_t)i+1]; r.z = pts[3*(size_t)i+2];
            r.w = __int_as_float(i);
            recA[pos] = r;
            vA[pos] = (unsigned)vv[k];
        }
    }
}

// ---- K_main_b: XCD-affine interpolation directly over bucket regions ----
// blockIdx = (c*256 + j)*8 + x; bucket b = 8c + x -> all 256 blocks of a
// bucket share (heuristically) one XCD -> its ~1 MB emb line set dedups in
// that XCD's L2. 64 points/block (4 lanes/point), CAP = 16384 = 2^14.
__global__ __launch_bounds__(256) void k_main_b(
    const unsigned* __restrict__ gbase,
    const unsigned* __restrict__ vA,
    const v4f*      __restrict__ recA,
    const float* __restrict__ emb,   // (N_EMB,16)
    const float* __restrict__ cp,    // (N_VOX,3)
    const int*   __restrict__ c2c,   // (N_VOX,8)
    const float* __restrict__ vox,
    float*       __restrict__ out,   // (N,16)
    int NB)
{
    const int bid = blockIdx.x;
    const int x   = bid & 7;
    const int t2  = bid >> 3;
    const int c   = t2 >> 8;
    const int j   = t2 & 255;
    const int b   = (c << 3) | x;
    if (b >= NB) return;

    const unsigned base = (unsigned)b << 14;
    const unsigned cntb = gbase[b] - base;          // end cursor - start
    const unsigned local = (unsigned)(j << 6) + (threadIdx.x >> 2);
    if (local >= cntb) return;

    const unsigned n = base + local;
    const int q = threadIdx.x & 3;

    const unsigned v = vA[n];
    const v4f r = recA[n];
    const int orig = __float_as_int(r.w);

    const int4* c4 = (const int4*)(c2c + 8 * (size_t)v);
    const int4 ci0 = c4[0];
    const int4 ci1 = c4[1];
    const int cidx[8] = {ci0.x, ci0.y, ci0.z, ci0.w, ci1.x, ci1.y, ci1.z, ci1.w};

    v4f e[8];
    #pragma unroll
    for (int cc = 0; cc < 8; ++cc) {
        e[cc] = *(const v4f*)(emb + 16 * (size_t)cidx[cc] + 4 * q);
    }

    const float inv_vs = 1.0f / vox[0];
    const float* cpp = cp + 3 * (size_t)v;
    const float px = (r.x - cpp[0]) * inv_vs + 0.5f;
    const float py = (r.y - cpp[1]) * inv_vs + 0.5f;
    const float pz = (r.z - cpp[2]) * inv_vs + 0.5f;
    const float wx[2] = {1.0f - px, px};
    const float wy[2] = {1.0f - py, py};
    const float wz[2] = {1.0f - pz, pz};

    v4f acc = (v4f)(0.0f);
    #pragma unroll
    for (int cc = 0; cc < 8; ++cc) {
        const float w = wx[(cc >> 2) & 1] * wy[(cc >> 1) & 1] * wz[cc & 1];
        acc.x = fmaf(w, e[cc].x, acc.x);
        acc.y = fmaf(w, e[cc].y, acc.y);
        acc.z = fmaf(w, e[cc].z, acc.z);
        acc.w = fmaf(w, e[cc].w, acc.w);
    }

    __builtin_nontemporal_store(acc, (v4f*)(out + 16 * (size_t)orig + 4 * q));
}

// ==================== FALLBACK PATH (r4, 52 MB ws) ====================

__global__ void k_zero(unsigned* __restrict__ hist, int n) {
    int i = blockIdx.x * blockDim.x + threadIdx.x;
    if (i < n) hist[i] = 0u;
}

__global__ __launch_bounds__(256) void k_hist_rank(const int* __restrict__ p2v,
                                                   unsigned* __restrict__ hist,
                                                   unsigned* __restrict__ rank, int N) {
    const int base = (blockIdx.x * blockDim.x + threadIdx.x) * 8;
    if (base + 7 < N) {
        const int4 a = *(const int4*)(p2v + base);
        const int4 b = *(const int4*)(p2v + base + 4);
        const unsigned r0 = atomicAdd(&hist[a.x], 1u);
        const unsigned r1 = atomicAdd(&hist[a.y], 1u);
        const unsigned r2 = atomicAdd(&hist[a.z], 1u);
        const unsigned r3 = atomicAdd(&hist[a.w], 1u);
        const unsigned r4 = atomicAdd(&hist[b.x], 1u);
        const unsigned r5 = atomicAdd(&hist[b.y], 1u);
        const unsigned r6 = atomicAdd(&hist[b.z], 1u);
        const unsigned r7 = atomicAdd(&hist[b.w], 1u);
        uint4 o0; o0.x = r0; o0.y = r1; o0.z = r2; o0.w = r3;
        uint4 o1; o1.x = r4; o1.y = r5; o1.z = r6; o1.w = r7;
        *(uint4*)(rank + base)     = o0;
        *(uint4*)(rank + base + 4) = o1;
    } else {
        for (int k = 0; k < 8; ++k)
            if (base + k < N) rank[base + k] = atomicAdd(&hist[p2v[base + k]], 1u);
    }
}

__global__ __launch_bounds__(256) void k_scan_blocks(unsigned* __restrict__ hist,
                                                     unsigned* __restrict__ bsums, int nbins) {
    __shared__ unsigned tsum[256];
    const int tid = threadIdx.x;
    const int i0 = blockIdx.x * 1024 + tid * 4;
    unsigned v[4]; unsigned s = 0;
    #pragma unroll
    for (int k = 0; k < 4; ++k) {
        unsigned c = (i0 + k < nbins) ? hist[i0 + k] : 0u;
        v[k] = s; s += c;
    }
    tsum[tid] = s; __syncthreads();
    for (int off = 1; off < 256; off <<= 1) {
        unsigned x = tsum[tid];
        unsigned y = (tid >= off) ? tsum[tid - off] : 0u;
        __syncthreads();
        tsum[tid] = x + y;
        __syncthreads();
    }
    unsigned prefix = (tid > 0) ? tsum[tid - 1] : 0u;
    #pragma unroll
    for (int k = 0; k < 4; ++k) {
        if (i0 + k < nbins) hist[i0 + k] = prefix + v[k];
    }
    if (tid == 255) bsums[blockIdx.x] = tsum[255];
}

__global__ __launch_bounds__(256) void k_scan_sums(unsigned* __restrict__ bsums, int nb) {
    __shared__ unsigned tsum[256];
    const int tid = threadIdx.x;
    const int i0 = tid * 4;
    unsigned v[4]; unsigned s = 0;
    #pragma unroll
    for (int k = 0; k < 4; ++k) {
        unsigned c = (i0 + k < nb) ? bsums[i0 + k] : 0u;
        v[k] = s; s += c;
    }
    tsum[tid] = s; __syncthreads();
    for (int off = 1; off < 256; off <<= 1) {
        unsigned x = tsum[tid];
        unsigned y = (tid >= off) ? tsum[tid - off] : 0u;
        __syncthreads();
        tsum[tid] = x + y;
        __syncthreads();
    }
    unsigned prefix = (tid > 0) ? tsum[tid - 1] : 0u;
    #pragma unroll
    for (int k = 0; k < 4; ++k) {
        if (i0 + k < nb) bsums[i0 + k] = prefix + v[k];
    }
}

__global__ __launch_bounds__(256) void k_place(
    const float* __restrict__ pts,
    const int*   __restrict__ p2v,
    const unsigned* __restrict__ rank,
    const unsigned* __restrict__ hist,
    const unsigned* __restrict__ bsums,
    unsigned* __restrict__ vsort,
    v4f*      __restrict__ rec,
    int N)
{
    const int base = (blockIdx.x * blockDim.x + threadIdx.x) * 4;
    if (base + 3 < N) {
        const int4  v4r = *(const int4*)(p2v + base);
        const uint4 r4  = *(const uint4*)(rank + base);
        const v4f* p4 = (const v4f*)pts;
        const size_t f0i = (size_t)(3 * (base >> 2));
        const v4f f0 = p4[f0i];
        const v4f f1 = p4[f0i + 1];
        const v4f f2 = p4[f0i + 2];

        const unsigned pos0 = hist[v4r.x] + bsums[((unsigned)v4r.x) >> 10] + r4.x;
        const unsigned pos1 = hist[v4r.y] + bsums[((unsigned)v4r.y) >> 10] + r4.y;
        const unsigned pos2 = hist[v4r.z] + bsums[((unsigned)v4r.z) >> 10] + r4.z;
        const unsigned pos3 = hist[v4r.w] + bsums[((unsigned)v4r.w) >> 10] + r4.w;

        vsort[pos0] = (unsigned)v4r.x;
        vsort[pos1] = (unsigned)v4r.y;
        vsort[pos2] = (unsigned)v4r.z;
        vsort[pos3] = (unsigned)v4r.w;

        v4f a;
        a.x = f0.x; a.y = f0.y; a.z = f0.z; a.w = __int_as_float(base + 0);
        rec[pos0] = a;
        a.x = f0.w; a.y = f1.x; a.z = f1.y; a.w = __int_as_float(base + 1);
        rec[pos1] = a;
        a.x = f1.z; a.y = f1.w; a.z = f2.x; a.w = __int_as_float(base + 2);
        rec[pos2] = a;
        a.x = f2.y; a.y = f2.z; a.z = f2.w; a.w = __int_as_float(base + 3);
        rec[pos3] = a;
    } else {
        for (int k = 0; k < 4; ++k) {
            const int i = base + k;
            if (i >= N) break;
            const int v = p2v[i];
            const unsigned pos = hist[v] + bsums[((unsigned)v) >> 10] + rank[i];
            vsort[pos] = (unsigned)v;
            v4f r;
            r.x = pts[3 * (size_t)i + 0];
            r.y = pts[3 * (size_t)i + 1];
            r.z = pts[3 * (size_t)i + 2];
            r.w = __int_as_float(i);
            rec[pos] = r;
        }
    }
}

// ---- K_main (range version): used by the fallback path ----
__global__ __launch_bounds__(256) void k_main(
    const unsigned* __restrict__ vsort, const v4f* __restrict__ rec,
    const float* __restrict__ emb,
    const float* __restrict__ cp,
    const int*   __restrict__ c2c,
    const float* __restrict__ vox,
    float*       __restrict__ out,
    int n0, int n1)
{
    const int t = blockIdx.x * blockDim.x + threadIdx.x;
    const int n = n0 + (t >> 2);
    const int q = t & 3;
    if (n >= n1) return;

    const unsigned v = vsort[n];
    const v4f r = rec[n];
    const int orig = __float_as_int(r.w);

    const int4* c4 = (const int4*)(c2c + 8 * (size_t)v);
    const int4 ci0 = c4[0];
    const int4 ci1 = c4[1];
    const int cidx[8] = {ci0.x, ci0.y, ci0.z, ci0.w, ci1.x, ci1.y, ci1.z, ci1.w};

    v4f e[8];
    #pragma unroll
    for (int c = 0; c < 8; ++c) {
        e[c] = *(const v4f*)(emb + 16 * (size_t)cidx[c] + 4 * q);
    }

    const float inv_vs = 1.0f / vox[0];
    const float* cpp = cp + 3 * (size_t)v;
    const float px = (r.x - cpp[0]) * inv_vs + 0.5f;
    const float py = (r.y - cpp[1]) * inv_vs + 0.5f;
    const float pz = (r.z - cpp[2]) * inv_vs + 0.5f;
    const float wx[2] = {1.0f - px, px};
    const float wy[2] = {1.0f - py, py};
    const float wz[2] = {1.0f - pz, pz};

    v4f acc = (v4f)(0.0f);
    #pragma unroll
    for (int c = 0; c < 8; ++c) {
        const float w = wx[(c >> 2) & 1] * wy[(c >> 1) & 1] * wz[c & 1];
        acc.x = fmaf(w, e[c].x, acc.x);
        acc.y = fmaf(w, e[c].y, acc.y);
        acc.z = fmaf(w, e[c].z, acc.z);
        acc.w = fmaf(w, e[c].w, acc.w);
    }

    __builtin_nontemporal_store(acc, (v4f*)(out + 16 * (size_t)orig + 4 * q));
}

__global__ __launch_bounds__(256) void k_direct(
    const float* __restrict__ pts, const int* __restrict__ p2v,
    const float* __restrict__ emb, const float* __restrict__ cp,
    const int* __restrict__ c2c, const float* __restrict__ vox,
    float* __restrict__ out, int N)
{
    const int t = blockIdx.x * blockDim.x + threadIdx.x;
    const int n = t >> 2, q = t & 3;
    if (n >= N) return;
    const int v = p2v[n];
    const int4* c4 = (const int4*)(c2c + 8 * (size_t)v);
    const int4 ci0 = c4[0], ci1 = c4[1];
    const int cidx[8] = {ci0.x, ci0.y, ci0.z, ci0.w, ci1.x, ci1.y, ci1.z, ci1.w};
    v4f e[8];
    #pragma unroll
    for (int c = 0; c < 8; ++c) e[c] = *(const v4f*)(emb + 16 * (size_t)cidx[c] + 4 * q);
    const float inv_vs = 1.0f / vox[0];
    const float* pp = pts + 3 * (size_t)n;
    const float* cpp = cp + 3 * (size_t)v;
    const float px = (pp[0] - cpp[0]) * inv_vs + 0.5f;
    const float py = (pp[1] - cpp[1]) * inv_vs + 0.5f;
    const float pz = (pp[2] - cpp[2]) * inv_vs + 0.5f;
    const float wx[2] = {1.0f - px, px};
    const float wy[2] = {1.0f - py, py};
    const float wz[2] = {1.0f - pz, pz};
    v4f acc = (v4f)(0.0f);
    #pragma unroll
    for (int c = 0; c < 8; ++c) {
        const float w = wx[(c >> 2) & 1] * wy[(c >> 1) & 1] * wz[c & 1];
        acc.x = fmaf(w, e[c].x, acc.x); acc.y = fmaf(w, e[c].y, acc.y);
        acc.z = fmaf(w, e[c].z, acc.z); acc.w = fmaf(w, e[c].w, acc.w);
    }
    __builtin_nontemporal_store(acc, (v4f*)(out + 4 * (size_t)t));
}

// ==================== LAUNCHER ====================

extern "C" void kernel_launch(void* const* d_in, const int* in_sizes, int n_in,
                              void* d_out, int out_size, void* d_ws, size_t ws_size,
                              hipStream_t stream) {
    const float* pts = (const float*)d_in[0];
    const int*   p2v = (const int*)d_in[1];
    const float* emb = (const float*)d_in[2];
    const float* cp  = (const float*)d_in[3];
    const int*   c2c = (const int*)d_in[4];
    const float* vox = (const float*)d_in[5];
    float*       out = (float*)d_out;

    const int N  = in_sizes[1];       // 2,000,000 points
    const int NV = in_sizes[4] / 8;   // 500,000 voxels
    const int block = 256;

    // ---------- fast path: bucket grouping + XCD-affine interp ----------
    const int NB = (NV + 2047) >> 11;                 // buckets of 2048 bins
    const unsigned CAP = 16384u;                      // 2^14, >> max bucket fill
    if (NB >= 1 && NB <= 512 && (unsigned)(N / NB) + 2048u <= CAP) {
        const size_t off_gbase = 0;                               // 512*4
        const size_t off_vA    = 8192;
        const size_t sz_vA     = (size_t)NB * CAP * 4u;
        const size_t off_recA  = (off_vA + sz_vA + 255u) & ~(size_t)255u;
        const size_t need_fast = off_recA + (size_t)NB * CAP * 16u;

        if (ws_size >= need_fast) {
            unsigned* gbase = (unsigned*)((char*)d_ws + off_gbase);
            unsigned* vA    = (unsigned*)((char*)d_ws + off_vA);
            v4f*      recA  = (v4f*)((char*)d_ws + off_recA);

            k_init_gbase<<<(NB + block - 1) / block, block, 0, stream>>>(gbase, NB, CAP);
            k_bucket<<<(N + 8191) / 8192, 1024, 0, stream>>>(p2v, pts, gbase, vA, recA, N, NB);

            const int classes = (NB + 7) >> 3;        // buckets per XCD class
            const int grid = 8 * classes * 256;       // 256 blocks per bucket
            k_main_b<<<grid, block, 0, stream>>>(
                gbase, vA, recA, emb, cp, c2c, vox, out, NB);
            return;
        }
    }

    // ---------- fallback: r4 pipeline (52 MB ws) ----------
    {
        const size_t MB = 1024u * 1024u;
        const size_t off_hist  = 0;                 // NV*4 (2 MB)
        const size_t off_bsums = 2u * MB;
        const size_t off_rank  = 4u * MB;           // N*4 (8 MB)
        const size_t off_vsort = 12u * MB;          // N*4 (8 MB)
        const size_t off_rec   = 20u * MB;          // N*16 (32 MB)
        const size_t need = off_rec + (size_t)N * 16u;

        if (ws_size >= need) {
            unsigned* hist  = (unsigned*)((char*)d_ws + off_hist);
            unsigned* bsums = (unsigned*)((char*)d_ws + off_bsums);
            unsigned* rank  = (unsigned*)((char*)d_ws + off_rank);
            unsigned* vsort = (unsigned*)((char*)d_ws + off_vsort);
            v4f*      rec   = (v4f*)((char*)d_ws + off_rec);

            const int nscan = (NV + 1023) / 1024;

            k_zero<<<(NV + block - 1) / block, block, 0, stream>>>(hist, NV);
            k_hist_rank<<<(N + block * 8 - 1) / (block * 8), block, 0, stream>>>(p2v, hist, rank, N);
            k_scan_blocks<<<nscan, 256, 0, stream>>>(hist, bsums, NV);
            k_scan_sums<<<1, 256, 0, stream>>>(bsums, nscan);
            k_place<<<(N + block * 4 - 1) / (block * 4), block, 0, stream>>>(
                pts, p2v, rank, hist, bsums, vsort, rec, N);

            const long long threads = 4LL * N;
            k_main<<<(int)((threads + block - 1) / block), block, 0, stream>>>(
                vsort, rec, emb, cp, c2c, vox, out, 0, N);
            return;
        }
    }

    // ---------- last resort ----------
    {
        const long long threads = 4LL * N;
        k_direct<<<(int)((threads + block - 1) / block), block, 0, stream>>>(
            pts, p2v, emb, cp, c2c, vox, out, N);
    }
}